// Round 3
// baseline (730.583 us; speedup 1.0000x reference)
//
#include <hip/hip_runtime.h>
#include <hip/hip_bf16.h>

#define T_SEQ 4096
#define CDIM  768
#define BDIM  8
#define MROWS (BDIM * T_SEQ)   // 32768
#define NKVR  (3 * CDIM)       // 2304
#define CHL   64               // chunk length (== one raster row)
#define NCH   (T_SEQ / CHL)    // 64 chunks
#define BC    (BDIM * CDIM)    // 6144 independent recurrences

typedef __attribute__((ext_vector_type(8))) short   short8;
typedef __attribute__((ext_vector_type(4))) float   floatx4;
typedef unsigned short ushort_t;
struct ushort4_t { ushort_t x, y, z, w; };

__device__ __forceinline__ ushort_t f2b(float f) {
    __hip_bfloat16 h = __float2bfloat16(f);
    return *(ushort_t*)&h;
}
__device__ __forceinline__ float b2f(ushort_t s) {
    __hip_bfloat16 h;
    *(ushort_t*)&h = s;
    return __bfloat162float(h);
}

__device__ __forceinline__ void gload_lds16(const void* g, void* l) {
    __builtin_amdgcn_global_load_lds(
        (const __attribute__((address_space(1))) void*)g,
        (__attribute__((address_space(3))) void*)l, 16, 0, 0);
}

// SHIFTS table: channel group i = c/32 gets shift (dy, dx); out[y][x] = in[y-dy][x-dx]
__constant__ int c_dy[24] = {0,0,1,-1,1,-1,1,-1,0,0,2,-2,2,-2,2,-2,2,1,2,1,-2,-1,-2,-1};
__constant__ int c_dx[24] = {1,-1,0,0,1,-1,-1,1,2,-2,0,0,2,-2,-2,2,1,2,-1,-2,1,2,-1,-2};

// ---------------------------------------------------------------- weights -> bf16
__global__ void cvt_weights(const float* __restrict__ kw, const float* __restrict__ vw,
                            const float* __restrict__ rw, const float* __restrict__ ow,
                            ushort_t* __restrict__ wkvr, ushort_t* __restrict__ wo) {
    int i = blockIdx.x * 256 + threadIdx.x;
    if (i < CDIM * CDIM) {
        wkvr[i]                   = f2b(kw[i]);
        wkvr[i + CDIM * CDIM]     = f2b(vw[i]);
        wkvr[i + 2 * CDIM * CDIM] = f2b(rw[i]);
        wo[i]                     = f2b(ow[i]);
    }
}

// ------------------------------------------------- shift + zigzag reorder + bf16
// vectorized by 4 channels (channel groups are 32-wide, so a c4 span never
// crosses a shift-group boundary)
__global__ void shift_zigzag(const float* __restrict__ x, ushort_t* __restrict__ xs) {
    size_t i = (size_t)blockIdx.x * 256 + threadIdx.x;   // over MROWS*CDIM/4
    if (i >= (size_t)MROWS * (CDIM / 4)) return;
    int c4 = (int)(i % (CDIM / 4)) * 4;
    size_t bt = i / (CDIM / 4);
    int tz = (int)(bt % T_SEQ);
    int b  = (int)(bt / T_SEQ);
    int r = tz >> 6, pos = tz & 63;
    int xcol = (r & 1) ? (63 - pos) : pos;
    int g = c4 >> 5;
    int ys = r - c_dy[g];
    int xsrc = xcol - c_dx[g];
    float4 val = {0.f, 0.f, 0.f, 0.f};
    if ((unsigned)ys < 64u && (unsigned)xsrc < 64u)
        val = *(const float4*)(x + ((size_t)b * T_SEQ + (size_t)(ys * 64 + xsrc)) * CDIM + c4);
    ushort4_t o;
    o.x = f2b(val.x); o.y = f2b(val.y); o.z = f2b(val.z); o.w = f2b(val.w);
    *(ushort4_t*)(xs + bt * CDIM + c4) = o;
}

// ---------------------------------------------------------------- bf16 MFMA GEMM
// C[m,n] = sum_k A[m,k] * W[n,k]; 128x128 tile, BK=32, 256 threads (4 waves 2x2).
// grid.x = n-blocks (N-major dispatch: weight panel stays L2-hot, A read once).
// LDS XOR swizzle: slot s = kc ^ ((row>>1)&3) -> 2-way bank aliasing (free).
template <int MODE>
__global__ __launch_bounds__(256) void gemm_bt(
    const ushort_t* __restrict__ A, const ushort_t* __restrict__ Bw,
    float* __restrict__ out_k, float* __restrict__ out_v,
    ushort_t* __restrict__ out_sr, float* __restrict__ out_f) {
    __shared__ ushort_t As[128 * 32];
    __shared__ ushort_t Bs[128 * 32];
    const int t    = threadIdx.x;
    const int n0   = blockIdx.x * 128;
    const int m0   = blockIdx.y * 128;
    const int lane = t & 63;
    const int wv   = t >> 6;
    const int wm   = (wv & 1) * 64;
    const int wn   = (wv >> 1) * 64;
    const int srow = t >> 2;                       // 0..63
    const int skc  = (t & 3) ^ ((srow >> 1) & 3);  // swizzled source chunk
    const int kb   = skc * 8;                      // element offset in K-slice
    const int l15  = lane & 15;
    const int l4   = lane >> 4;

    floatx4 acc[4][4];
#pragma unroll
    for (int i = 0; i < 4; i++)
#pragma unroll
        for (int j = 0; j < 4; j++) acc[i][j] = (floatx4){0.f, 0.f, 0.f, 0.f};

    for (int kk = 0; kk < CDIM; kk += 32) {
        __syncthreads();
        gload_lds16(A  + (size_t)(m0 + srow)      * CDIM + kk + kb, (void*)(As + t * 8));
        gload_lds16(A  + (size_t)(m0 + 64 + srow) * CDIM + kk + kb, (void*)(As + 2048 + t * 8));
        gload_lds16(Bw + (size_t)(n0 + srow)      * CDIM + kk + kb, (void*)(Bs + t * 8));
        gload_lds16(Bw + (size_t)(n0 + 64 + srow) * CDIM + kk + kb, (void*)(Bs + 2048 + t * 8));
        __syncthreads();
        short8 af[4], bfv[4];
#pragma unroll
        for (int mi = 0; mi < 4; mi++) {
            int ra = wm + mi * 16 + l15;
            af[mi] = *(const short8*)(As + ra * 32 + ((l4 ^ ((ra >> 1) & 3)) << 3));
        }
#pragma unroll
        for (int ni = 0; ni < 4; ni++) {
            int rb = wn + ni * 16 + l15;
            bfv[ni] = *(const short8*)(Bs + rb * 32 + ((l4 ^ ((rb >> 1) & 3)) << 3));
        }
#pragma unroll
        for (int mi = 0; mi < 4; mi++)
#pragma unroll
            for (int ni = 0; ni < 4; ni++)
                acc[mi][ni] = __builtin_amdgcn_mfma_f32_16x16x32_bf16(
                    af[mi], bfv[ni], acc[mi][ni], 0, 0, 0);
    }

#pragma unroll
    for (int mi = 0; mi < 4; mi++) {
#pragma unroll
        for (int ni = 0; ni < 4; ni++) {
            int ng = n0 + wn + ni * 16 + l15;
#pragma unroll
            for (int r = 0; r < 4; r++) {
                int mg = m0 + wm + mi * 16 + l4 * 4 + r;
                float val = acc[mi][ni][r];
                if (MODE == 0) {
                    if (ng < CDIM)
                        out_k[(size_t)mg * CDIM + ng] = val;
                    else if (ng < 2 * CDIM)
                        out_v[(size_t)mg * CDIM + (ng - CDIM)] = val;
                    else
                        out_sr[(size_t)mg * CDIM + (ng - 2 * CDIM)] =
                            f2b(1.0f / (1.0f + __expf(-val)));
                } else {
                    out_f[(size_t)mg * CDIM + ng] = val;
                }
            }
        }
    }
}

// ------------------------------------------------------------- WKV chunked scan
// Recurrence: P' = e^w P + e^{k} v ; state kept max-normalized as (p,q,o).
// PASS 0: sequence = zigzag row order (identity on buffer rows).
// PASS 1: sequence = raster order; step in chunk ch visits row ch*64 + (ch odd ? 63-i : i).

// Phase A (pass 0 only): per-chunk local summary from empty state.
__global__ __launch_bounds__(256) void wkv_chunk_sum0(
    const float* __restrict__ kbuf, const float* __restrict__ vbuf,
    const float* __restrict__ sd,
    float* __restrict__ sumP, float* __restrict__ sumQ, float* __restrict__ sumO) {
    int gid = blockIdx.x * 256 + threadIdx.x;
    int bc = gid % BC;
    int ch = gid / BC;
    int b = bc / CDIM, c = bc % CDIM;
    const float w = sd[c] * (1.0f / (float)T_SEQ);
    size_t base = (size_t)b * T_SEQ * CDIM + c + (size_t)ch * CHL * CDIM;
    float p = 0.f, q = 0.f, o = -1e38f;
#pragma unroll 4
    for (int i = 0; i < CHL; i++) {
        size_t off = base + (size_t)i * CDIM;
        float kt = kbuf[off], vt = vbuf[off];
        float wo_ = w + o;
        float no2 = fmaxf(wo_, kt);
        float A2 = __expf(wo_ - no2), B2 = __expf(kt - no2);
        p = A2 * p + B2 * vt;
        q = A2 * q + B2;
        o = no2;
    }
    size_t idx = (size_t)ch * BC + bc;
    sumP[idx] = p; sumQ[idx] = q; sumO[idx] = o;
}

// Phase B: sequential combine of chunk summaries; writes incoming state per chunk.
__global__ __launch_bounds__(256) void wkv_chunk_scan(
    const float* __restrict__ sumP, const float* __restrict__ sumQ,
    const float* __restrict__ sumO,
    float* __restrict__ inP, float* __restrict__ inQ, float* __restrict__ inO,
    const float* __restrict__ sd, int pass) {
    int bc = blockIdx.x * 256 + threadIdx.x;
    if (bc >= BC) return;
    int c = bc % CDIM;
    const float w = sd[pass * CDIM + c] * (1.0f / (float)T_SEQ);
    const float Lw = w * (float)CHL;
    float p = 0.f, q = 0.f, o = -1e38f;
    for (int ch = 0; ch < NCH; ch++) {
        size_t idx = (size_t)ch * BC + bc;
        inP[idx] = p; inQ[idx] = q; inO[idx] = o;
        float Pc = sumP[idx], Qc = sumQ[idx], Oc = sumO[idx];
        float ow_ = o + Lw;
        float no = fmaxf(ow_, Oc);
        float e1 = __expf(ow_ - no), e2 = __expf(Oc - no);
        p = e1 * p + e2 * Pc;
        q = e1 * q + e2 * Qc;
        o = no;
    }
}

// Phase C fused: replay pass-1 chunk (emit y -> vbuf, y kept in registers),
// then compute pass-2 chunk summary over the same 64 rows in raster order.
__global__ __launch_bounds__(256) void wkv_replay0_sum1(
    const float* __restrict__ kbuf, float* __restrict__ vbuf,
    const float* __restrict__ sd, const float* __restrict__ sf,
    const float* __restrict__ inP, const float* __restrict__ inQ,
    const float* __restrict__ inO,
    float* __restrict__ sumP, float* __restrict__ sumQ, float* __restrict__ sumO) {
    int gid = blockIdx.x * 256 + threadIdx.x;
    int bc = gid % BC;
    int ch = gid / BC;
    int b = bc / CDIM, c = bc % CDIM;
    const float w1 = sd[c] * (1.0f / (float)T_SEQ);
    const float u1 = sf[c] * (1.0f / (float)T_SEQ);
    size_t base = (size_t)b * T_SEQ * CDIM + c + (size_t)ch * CHL * CDIM;
    size_t idx = (size_t)ch * BC + bc;
    float p = inP[idx], q = inQ[idx], o = inO[idx];
    float yv[CHL];
    float kv[CHL];
#pragma unroll 4
    for (int i = 0; i < CHL; i++) {
        size_t off = base + (size_t)i * CDIM;
        float kt = kbuf[off], vt = vbuf[off];
        kv[i] = kt;
        float uk = u1 + kt;
        float no = fmaxf(o, uk);
        float Ae = __expf(o - no), Be = __expf(uk - no);
        float y = (Ae * p + Be * vt) / (Ae * q + Be);
        float wo_ = w1 + o;
        float no2 = fmaxf(wo_, kt);
        float A2 = __expf(wo_ - no2), B2 = __expf(kt - no2);
        p = A2 * p + B2 * vt;
        q = A2 * q + B2;
        o = no2;
        yv[i] = y;
        vbuf[off] = y;
    }
    // pass-2 summary over the same rows, raster traversal (reverse for odd ch)
    const float w2 = sd[CDIM + c] * (1.0f / (float)T_SEQ);
    float p2 = 0.f, q2 = 0.f, o2 = -1e38f;
    if (ch & 1) {
#pragma unroll 4
        for (int i = CHL - 1; i >= 0; i--) {
            float kt = kv[i], vt = yv[i];
            float wo_ = w2 + o2;
            float no2 = fmaxf(wo_, kt);
            float A2 = __expf(wo_ - no2), B2 = __expf(kt - no2);
            p2 = A2 * p2 + B2 * vt;
            q2 = A2 * q2 + B2;
            o2 = no2;
        }
    } else {
#pragma unroll 4
        for (int i = 0; i < CHL; i++) {
            float kt = kv[i], vt = yv[i];
            float wo_ = w2 + o2;
            float no2 = fmaxf(wo_, kt);
            float A2 = __expf(wo_ - no2), B2 = __expf(kt - no2);
            p2 = A2 * p2 + B2 * vt;
            q2 = A2 * q2 + B2;
            o2 = no2;
        }
    }
    sumP[idx] = p2; sumQ[idx] = q2; sumO[idx] = o2;
}

// Phase C (pass 1): replay raster-order chunk, emit a2 = bf16(y * sr).
__global__ __launch_bounds__(256) void wkv_replay1(
    const float* __restrict__ kbuf, const float* __restrict__ vbuf,
    const ushort_t* __restrict__ srb, ushort_t* __restrict__ a2,
    const float* __restrict__ sd, const float* __restrict__ sf,
    const float* __restrict__ inP, const float* __restrict__ inQ,
    const float* __restrict__ inO) {
    int gid = blockIdx.x * 256 + threadIdx.x;
    int bc = gid % BC;
    int ch = gid / BC;
    int b = bc / CDIM, c = bc % CDIM;
    const float w = sd[CDIM + c] * (1.0f / (float)T_SEQ);
    const float u = sf[CDIM + c] * (1.0f / (float)T_SEQ);
    size_t base = (size_t)b * T_SEQ * CDIM + c;
    size_t idx = (size_t)ch * BC + bc;
    float p = inP[idx], q = inQ[idx], o = inO[idx];
#pragma unroll 4
    for (int i = 0; i < CHL; i++) {
        int row = ch * CHL + ((ch & 1) ? (CHL - 1 - i) : i);
        size_t off = base + (size_t)row * CDIM;
        float kt = kbuf[off], vt = vbuf[off];
        float uk = u + kt;
        float no = fmaxf(o, uk);
        float Ae = __expf(o - no), Be = __expf(uk - no);
        float y = (Ae * p + Be * vt) / (Ae * q + Be);
        float wo_ = w + o;
        float no2 = fmaxf(wo_, kt);
        float A2 = __expf(wo_ - no2), B2 = __expf(kt - no2);
        p = A2 * p + B2 * vt;
        q = A2 * q + B2;
        o = no2;
        a2[off] = f2b(y * b2f(srb[off]));
    }
}

// ----------------------------------------------------------------------- launch
extern "C" void kernel_launch(void* const* d_in, const int* in_sizes, int n_in,
                              void* d_out, int out_size, void* d_ws, size_t ws_size,
                              hipStream_t stream) {
    (void)in_sizes; (void)n_in; (void)out_size; (void)ws_size;
    const float* x  = (const float*)d_in[0];
    const float* kw = (const float*)d_in[1];
    const float* vw = (const float*)d_in[2];
    const float* rw = (const float*)d_in[3];
    const float* ow = (const float*)d_in[4];
    const float* sd = (const float*)d_in[5];
    const float* sf = (const float*)d_in[6];
    float* out = (float*)d_out;

    char* ws = (char*)d_ws;
    size_t off = 0;
    auto alloc = [&](size_t bytes) -> void* {
        void* p = ws + off;
        off += (bytes + 255) & ~(size_t)255;
        return p;
    };
    ushort_t* xs   = (ushort_t*)alloc((size_t)MROWS * CDIM * 2);  // reused as a2
    float*    kbuf = (float*)   alloc((size_t)MROWS * CDIM * 4);
    float*    vbuf = (float*)   alloc((size_t)MROWS * CDIM * 4);
    ushort_t* srb  = (ushort_t*)alloc((size_t)MROWS * CDIM * 2);
    ushort_t* wkvr = (ushort_t*)alloc((size_t)NKVR * CDIM * 2);
    ushort_t* wo   = (ushort_t*)alloc((size_t)CDIM * CDIM * 2);
    float*    sumP = (float*)   alloc((size_t)NCH * BC * 4);
    float*    sumQ = (float*)   alloc((size_t)NCH * BC * 4);
    float*    sumO = (float*)   alloc((size_t)NCH * BC * 4);
    float*    inP  = (float*)   alloc((size_t)NCH * BC * 4);
    float*    inQ  = (float*)   alloc((size_t)NCH * BC * 4);
    float*    inO  = (float*)   alloc((size_t)NCH * BC * 4);

    cvt_weights<<<(CDIM * CDIM + 255) / 256, 256, 0, stream>>>(kw, vw, rw, ow, wkvr, wo);
    shift_zigzag<<<(int)(((size_t)MROWS * (CDIM / 4) + 255) / 256), 256, 0, stream>>>(x, xs);
    gemm_bt<0><<<dim3(NKVR / 128, MROWS / 128), 256, 0, stream>>>(
        xs, wkvr, kbuf, vbuf, srb, nullptr);

    const int nwkv = NCH * BC;  // 393216 threads
    // ---- pass 1 (zigzag order)
    wkv_chunk_sum0<<<nwkv / 256, 256, 0, stream>>>(kbuf, vbuf, sd, sumP, sumQ, sumO);
    wkv_chunk_scan<<<(BC + 255) / 256, 256, 0, stream>>>(sumP, sumQ, sumO,
                                                         inP, inQ, inO, sd, 0);
    // ---- fused: pass-1 replay (y -> vbuf) + pass-2 chunk summaries
    wkv_replay0_sum1<<<nwkv / 256, 256, 0, stream>>>(kbuf, vbuf, sd, sf,
                                                     inP, inQ, inO, sumP, sumQ, sumO);
    wkv_chunk_scan<<<(BC + 255) / 256, 256, 0, stream>>>(sumP, sumQ, sumO,
                                                         inP, inQ, inO, sd, 1);
    // ---- pass-2 replay, emits a2 = bf16(y * sr) into xs buffer
    wkv_replay1<<<nwkv / 256, 256, 0, stream>>>(kbuf, vbuf, srb, xs,
                                                sd, sf, inP, inQ, inO);

    gemm_bt<1><<<dim3(CDIM / 128, MROWS / 128), 256, 0, stream>>>(
        xs, wo, nullptr, nullptr, nullptr, out);
}

// Round 4
// 598.876 us; speedup vs baseline: 1.2199x; 1.2199x over previous
//
#include <hip/hip_runtime.h>
#include <hip/hip_bf16.h>
#include <hip/hip_fp16.h>

#define T_SEQ 4096
#define CDIM  768
#define BDIM  8
#define MROWS (BDIM * T_SEQ)   // 32768
#define NKVR  (3 * CDIM)       // 2304
#define CHL   64               // chunk length (== one raster row)
#define NCH   (T_SEQ / CHL)    // 64 chunks
#define BC    (BDIM * CDIM)    // 6144 independent recurrences

typedef __attribute__((ext_vector_type(8))) short   short8;
typedef __attribute__((ext_vector_type(4))) float   floatx4;
typedef unsigned short ushort_t;
struct ushort4_t { ushort_t x, y, z, w; };

__device__ __forceinline__ ushort_t f2b(float f) {
    __hip_bfloat16 h = __float2bfloat16(f);
    return *(ushort_t*)&h;
}
__device__ __forceinline__ float b2f(ushort_t s) {
    __hip_bfloat16 h;
    *(ushort_t*)&h = s;
    return __bfloat162float(h);
}
__device__ __forceinline__ ushort_t f2h(float f) {
    __half h = __float2half(f);
    return *(ushort_t*)&h;
}
__device__ __forceinline__ float h2f(ushort_t s) {
    __half h;
    *(ushort_t*)&h = s;
    return __half2float(h);
}

__device__ __forceinline__ void gload_lds16(const void* g, void* l) {
    __builtin_amdgcn_global_load_lds(
        (const __attribute__((address_space(1))) void*)g,
        (__attribute__((address_space(3))) void*)l, 16, 0, 0);
}

// SHIFTS table: channel group i = c/32 gets shift (dy, dx); out[y][x] = in[y-dy][x-dx]
__constant__ int c_dy[24] = {0,0,1,-1,1,-1,1,-1,0,0,2,-2,2,-2,2,-2,2,1,2,1,-2,-1,-2,-1};
__constant__ int c_dx[24] = {1,-1,0,0,1,-1,-1,1,2,-2,0,0,2,-2,-2,2,1,2,-1,-2,1,2,-1,-2};

// ---------------------------------------------------------------- weights -> bf16
__global__ void cvt_weights(const float* __restrict__ kw, const float* __restrict__ vw,
                            const float* __restrict__ rw, const float* __restrict__ ow,
                            ushort_t* __restrict__ wkvr, ushort_t* __restrict__ wo) {
    int i = blockIdx.x * 256 + threadIdx.x;
    if (i < CDIM * CDIM) {
        wkvr[i]                   = f2b(kw[i]);
        wkvr[i + CDIM * CDIM]     = f2b(vw[i]);
        wkvr[i + 2 * CDIM * CDIM] = f2b(rw[i]);
        wo[i]                     = f2b(ow[i]);
    }
}

// ------------------------------------------------- shift + zigzag reorder + bf16
__global__ void shift_zigzag(const float* __restrict__ x, ushort_t* __restrict__ xs) {
    size_t i = (size_t)blockIdx.x * 256 + threadIdx.x;   // over MROWS*CDIM/4
    if (i >= (size_t)MROWS * (CDIM / 4)) return;
    int c4 = (int)(i % (CDIM / 4)) * 4;
    size_t bt = i / (CDIM / 4);
    int tz = (int)(bt % T_SEQ);
    int b  = (int)(bt / T_SEQ);
    int r = tz >> 6, pos = tz & 63;
    int xcol = (r & 1) ? (63 - pos) : pos;
    int g = c4 >> 5;
    int ys = r - c_dy[g];
    int xsrc = xcol - c_dx[g];
    float4 val = {0.f, 0.f, 0.f, 0.f};
    if ((unsigned)ys < 64u && (unsigned)xsrc < 64u)
        val = *(const float4*)(x + ((size_t)b * T_SEQ + (size_t)(ys * 64 + xsrc)) * CDIM + c4);
    ushort4_t o;
    o.x = f2b(val.x); o.y = f2b(val.y); o.z = f2b(val.z); o.w = f2b(val.w);
    *(ushort4_t*)(xs + bt * CDIM + c4) = o;
}

// ---------------------------------------------------------------- bf16 MFMA GEMM
// C[m,n] = sum_k A[m,k] * W[n,k]; 128x128 tile, BK=32, 256 threads (4 waves 2x2).
// 1-D grid with XCD-aware swizzle: p%8 selects XCD; all NB n-blocks of one
// m-strip land on the same XCD so the A-strip + weight panel stay L2-hot.
// LDS XOR swizzle keeps bank aliasing at 2-way (free).
// MODE 0 (NB=18): nb 0..5 -> k (fp16), 6..11 -> v (fp16), 12..17 -> sigmoid(r) bf16.
// MODE 1 (NB=6): fp32 out.
template <int MODE, int NB>
__global__ __launch_bounds__(256, 3) void gemm_bt(
    const ushort_t* __restrict__ A, const ushort_t* __restrict__ Bw,
    ushort_t* __restrict__ out_k, ushort_t* __restrict__ out_v,
    ushort_t* __restrict__ out_sr, float* __restrict__ out_f) {
    __shared__ ushort_t As[128 * 32];
    __shared__ ushort_t Bs[128 * 32];
    const int p    = blockIdx.x;
    const int xcd  = p & 7;
    const int s    = p >> 3;
    const int mb   = xcd + 8 * (s / NB);
    const int nb   = s % NB;
    const int m0   = mb * 128;
    const int n0   = nb * 128;
    const int t    = threadIdx.x;
    const int lane = t & 63;
    const int wv   = t >> 6;
    const int wm   = (wv & 1) * 64;
    const int wn   = (wv >> 1) * 64;
    const int srow = t >> 2;                       // 0..63
    const int skc  = (t & 3) ^ ((srow >> 1) & 3);  // swizzled source chunk
    const int kb   = skc * 8;
    const int l15  = lane & 15;
    const int l4   = lane >> 4;

    floatx4 acc[4][4];
#pragma unroll
    for (int i = 0; i < 4; i++)
#pragma unroll
        for (int j = 0; j < 4; j++) acc[i][j] = (floatx4){0.f, 0.f, 0.f, 0.f};

    for (int kk = 0; kk < CDIM; kk += 32) {
        __syncthreads();
        gload_lds16(A  + (size_t)(m0 + srow)      * CDIM + kk + kb, (void*)(As + t * 8));
        gload_lds16(A  + (size_t)(m0 + 64 + srow) * CDIM + kk + kb, (void*)(As + 2048 + t * 8));
        gload_lds16(Bw + (size_t)(n0 + srow)      * CDIM + kk + kb, (void*)(Bs + t * 8));
        gload_lds16(Bw + (size_t)(n0 + 64 + srow) * CDIM + kk + kb, (void*)(Bs + 2048 + t * 8));
        __syncthreads();
        short8 af[4], bfv[4];
#pragma unroll
        for (int mi = 0; mi < 4; mi++) {
            int ra = wm + mi * 16 + l15;
            af[mi] = *(const short8*)(As + ra * 32 + ((l4 ^ ((ra >> 1) & 3)) << 3));
        }
#pragma unroll
        for (int ni = 0; ni < 4; ni++) {
            int rb = wn + ni * 16 + l15;
            bfv[ni] = *(const short8*)(Bs + rb * 32 + ((l4 ^ ((rb >> 1) & 3)) << 3));
        }
#pragma unroll
        for (int mi = 0; mi < 4; mi++)
#pragma unroll
            for (int ni = 0; ni < 4; ni++)
                acc[mi][ni] = __builtin_amdgcn_mfma_f32_16x16x32_bf16(
                    af[mi], bfv[ni], acc[mi][ni], 0, 0, 0);
    }

    // epilogue: region is uniform per block (128 | 768)
    const int region = (MODE == 0) ? (nb / 6) : 0;
    ushort_t* outh = (region == 0) ? out_k : (region == 1) ? out_v : out_sr;
    const int ncb = n0 - region * CDIM;
#pragma unroll
    for (int mi = 0; mi < 4; mi++) {
#pragma unroll
        for (int ni = 0; ni < 4; ni++) {
            int nc = ncb + wn + ni * 16 + l15;
#pragma unroll
            for (int r = 0; r < 4; r++) {
                int mg = m0 + wm + mi * 16 + l4 * 4 + r;
                float val = acc[mi][ni][r];
                if (MODE == 0) {
                    if (region < 2)
                        outh[(size_t)mg * CDIM + nc] = f2h(val);
                    else
                        outh[(size_t)mg * CDIM + nc] =
                            f2b(1.0f / (1.0f + __expf(-val)));
                } else {
                    out_f[(size_t)mg * CDIM + (n0 + wn + ni * 16 + l15)] = val;
                }
            }
        }
    }
}

// ------------------------------------------------------------- WKV chunked scan
// Recurrence: P' = e^w P + e^{k} v ; state kept max-normalized as (p,q,o).
// PASS 0: sequence = zigzag row order (identity on buffer rows).
// PASS 1: raster order; chunk ch visits row ch*64 + (ch odd ? 63-i : i).
// k, v, y stored fp16.

// Phase A (pass 0): per-chunk local summary from empty state.
__global__ __launch_bounds__(256) void wkv_chunk_sum0(
    const ushort_t* __restrict__ kbuf, const ushort_t* __restrict__ vbuf,
    const float* __restrict__ sd,
    float* __restrict__ sumP, float* __restrict__ sumQ, float* __restrict__ sumO) {
    int gid = blockIdx.x * 256 + threadIdx.x;
    int bc = gid % BC;
    int ch = gid / BC;
    int b = bc / CDIM, c = bc % CDIM;
    const float w = sd[c] * (1.0f / (float)T_SEQ);
    size_t base = (size_t)b * T_SEQ * CDIM + c + (size_t)ch * CHL * CDIM;
    float p = 0.f, q = 0.f, o = -1e38f;
#pragma unroll 4
    for (int i = 0; i < CHL; i++) {
        size_t off = base + (size_t)i * CDIM;
        float kt = h2f(kbuf[off]), vt = h2f(vbuf[off]);
        float wo_ = w + o;
        float no2 = fmaxf(wo_, kt);
        float A2 = __expf(wo_ - no2), B2 = __expf(kt - no2);
        p = A2 * p + B2 * vt;
        q = A2 * q + B2;
        o = no2;
    }
    size_t idx = (size_t)ch * BC + bc;
    sumP[idx] = p; sumQ[idx] = q; sumO[idx] = o;
}

// Phase B: sequential combine of chunk summaries; writes incoming state per chunk.
__global__ __launch_bounds__(256) void wkv_chunk_scan(
    const float* __restrict__ sumP, const float* __restrict__ sumQ,
    const float* __restrict__ sumO,
    float* __restrict__ inP, float* __restrict__ inQ, float* __restrict__ inO,
    const float* __restrict__ sd, int pass) {
    int bc = blockIdx.x * 256 + threadIdx.x;
    if (bc >= BC) return;
    int c = bc % CDIM;
    const float w = sd[pass * CDIM + c] * (1.0f / (float)T_SEQ);
    const float Lw = w * (float)CHL;
    float p = 0.f, q = 0.f, o = -1e38f;
    for (int ch = 0; ch < NCH; ch++) {
        size_t idx = (size_t)ch * BC + bc;
        inP[idx] = p; inQ[idx] = q; inO[idx] = o;
        float Pc = sumP[idx], Qc = sumQ[idx], Oc = sumO[idx];
        float ow_ = o + Lw;
        float no = fmaxf(ow_, Oc);
        float e1 = __expf(ow_ - no), e2 = __expf(Oc - no);
        p = e1 * p + e2 * Pc;
        q = e1 * q + e2 * Qc;
        o = no;
    }
}

// Phase C fused: replay pass-1 chunk (emit y -> vbuf fp16, y kept in regs),
// then compute pass-2 chunk summary over the same 64 rows in raster order.
__global__ __launch_bounds__(256) void wkv_replay0_sum1(
    const ushort_t* __restrict__ kbuf, ushort_t* __restrict__ vbuf,
    const float* __restrict__ sd, const float* __restrict__ sf,
    const float* __restrict__ inP, const float* __restrict__ inQ,
    const float* __restrict__ inO,
    float* __restrict__ sumP, float* __restrict__ sumQ, float* __restrict__ sumO) {
    int gid = blockIdx.x * 256 + threadIdx.x;
    int bc = gid % BC;
    int ch = gid / BC;
    int b = bc / CDIM, c = bc % CDIM;
    const float w1 = sd[c] * (1.0f / (float)T_SEQ);
    const float u1 = sf[c] * (1.0f / (float)T_SEQ);
    size_t base = (size_t)b * T_SEQ * CDIM + c + (size_t)ch * CHL * CDIM;
    size_t idx = (size_t)ch * BC + bc;
    float p = inP[idx], q = inQ[idx], o = inO[idx];
    float yv[CHL];
    float kv[CHL];
#pragma unroll 4
    for (int i = 0; i < CHL; i++) {
        size_t off = base + (size_t)i * CDIM;
        float kt = h2f(kbuf[off]), vt = h2f(vbuf[off]);
        kv[i] = kt;
        float uk = u1 + kt;
        float no = fmaxf(o, uk);
        float Ae = __expf(o - no), Be = __expf(uk - no);
        float y = (Ae * p + Be * vt) / (Ae * q + Be);
        float wo_ = w1 + o;
        float no2 = fmaxf(wo_, kt);
        float A2 = __expf(wo_ - no2), B2 = __expf(kt - no2);
        p = A2 * p + B2 * vt;
        q = A2 * q + B2;
        o = no2;
        yv[i] = y;
        vbuf[off] = f2h(y);
    }
    // pass-2 summary over the same rows, raster traversal (reverse for odd ch)
    const float w2 = sd[CDIM + c] * (1.0f / (float)T_SEQ);
    float p2 = 0.f, q2 = 0.f, o2 = -1e38f;
    if (ch & 1) {
#pragma unroll 4
        for (int i = CHL - 1; i >= 0; i--) {
            float kt = kv[i], vt = yv[i];
            float wo_ = w2 + o2;
            float no2 = fmaxf(wo_, kt);
            float A2 = __expf(wo_ - no2), B2 = __expf(kt - no2);
            p2 = A2 * p2 + B2 * vt;
            q2 = A2 * q2 + B2;
            o2 = no2;
        }
    } else {
#pragma unroll 4
        for (int i = 0; i < CHL; i++) {
            float kt = kv[i], vt = yv[i];
            float wo_ = w2 + o2;
            float no2 = fmaxf(wo_, kt);
            float A2 = __expf(wo_ - no2), B2 = __expf(kt - no2);
            p2 = A2 * p2 + B2 * vt;
            q2 = A2 * q2 + B2;
            o2 = no2;
        }
    }
    sumP[idx] = p2; sumQ[idx] = q2; sumO[idx] = o2;
}

// Phase C (pass 1): replay raster-order chunk, emit a2 = bf16(y * sr).
__global__ __launch_bounds__(256) void wkv_replay1(
    const ushort_t* __restrict__ kbuf, const ushort_t* __restrict__ vbuf,
    const ushort_t* __restrict__ srb, ushort_t* __restrict__ a2,
    const float* __restrict__ sd, const float* __restrict__ sf,
    const float* __restrict__ inP, const float* __restrict__ inQ,
    const float* __restrict__ inO) {
    int gid = blockIdx.x * 256 + threadIdx.x;
    int bc = gid % BC;
    int ch = gid / BC;
    int b = bc / CDIM, c = bc % CDIM;
    const float w = sd[CDIM + c] * (1.0f / (float)T_SEQ);
    const float u = sf[CDIM + c] * (1.0f / (float)T_SEQ);
    size_t base = (size_t)b * T_SEQ * CDIM + c;
    size_t idx = (size_t)ch * BC + bc;
    float p = inP[idx], q = inQ[idx], o = inO[idx];
#pragma unroll 4
    for (int i = 0; i < CHL; i++) {
        int row = ch * CHL + ((ch & 1) ? (CHL - 1 - i) : i);
        size_t off = base + (size_t)row * CDIM;
        float kt = h2f(kbuf[off]), vt = h2f(vbuf[off]);
        float uk = u + kt;
        float no = fmaxf(o, uk);
        float Ae = __expf(o - no), Be = __expf(uk - no);
        float y = (Ae * p + Be * vt) / (Ae * q + Be);
        float wo_ = w + o;
        float no2 = fmaxf(wo_, kt);
        float A2 = __expf(wo_ - no2), B2 = __expf(kt - no2);
        p = A2 * p + B2 * vt;
        q = A2 * q + B2;
        o = no2;
        a2[off] = f2b(y * b2f(srb[off]));
    }
}

// ----------------------------------------------------------------------- launch
extern "C" void kernel_launch(void* const* d_in, const int* in_sizes, int n_in,
                              void* d_out, int out_size, void* d_ws, size_t ws_size,
                              hipStream_t stream) {
    (void)in_sizes; (void)n_in; (void)out_size; (void)ws_size;
    const float* x  = (const float*)d_in[0];
    const float* kw = (const float*)d_in[1];
    const float* vw = (const float*)d_in[2];
    const float* rw = (const float*)d_in[3];
    const float* ow = (const float*)d_in[4];
    const float* sd = (const float*)d_in[5];
    const float* sf = (const float*)d_in[6];
    float* out = (float*)d_out;

    char* ws = (char*)d_ws;
    size_t off = 0;
    auto alloc = [&](size_t bytes) -> void* {
        void* p = ws + off;
        off += (bytes + 255) & ~(size_t)255;
        return p;
    };
    ushort_t* xs   = (ushort_t*)alloc((size_t)MROWS * CDIM * 2);  // reused as a2
    ushort_t* kbuf = (ushort_t*)alloc((size_t)MROWS * CDIM * 2);  // fp16
    ushort_t* vbuf = (ushort_t*)alloc((size_t)MROWS * CDIM * 2);  // fp16 (v then y)
    ushort_t* srb  = (ushort_t*)alloc((size_t)MROWS * CDIM * 2);  // bf16
    ushort_t* wkvr = (ushort_t*)alloc((size_t)NKVR * CDIM * 2);
    ushort_t* wo   = (ushort_t*)alloc((size_t)CDIM * CDIM * 2);
    float*    sumP = (float*)   alloc((size_t)NCH * BC * 4);
    float*    sumQ = (float*)   alloc((size_t)NCH * BC * 4);
    float*    sumO = (float*)   alloc((size_t)NCH * BC * 4);
    float*    inP  = (float*)   alloc((size_t)NCH * BC * 4);
    float*    inQ  = (float*)   alloc((size_t)NCH * BC * 4);
    float*    inO  = (float*)   alloc((size_t)NCH * BC * 4);

    cvt_weights<<<(CDIM * CDIM + 255) / 256, 256, 0, stream>>>(kw, vw, rw, ow, wkvr, wo);
    shift_zigzag<<<(int)(((size_t)MROWS * (CDIM / 4) + 255) / 256), 256, 0, stream>>>(x, xs);
    gemm_bt<0, 18><<<(MROWS / 128) * (NKVR / 128), 256, 0, stream>>>(
        xs, wkvr, kbuf, vbuf, srb, nullptr);

    const int nwkv = NCH * BC;  // 393216 threads
    // ---- pass 1 (zigzag order)
    wkv_chunk_sum0<<<nwkv / 256, 256, 0, stream>>>(kbuf, vbuf, sd, sumP, sumQ, sumO);
    wkv_chunk_scan<<<(BC + 255) / 256, 256, 0, stream>>>(sumP, sumQ, sumO,
                                                         inP, inQ, inO, sd, 0);
    // ---- fused: pass-1 replay (y -> vbuf) + pass-2 chunk summaries
    wkv_replay0_sum1<<<nwkv / 256, 256, 0, stream>>>(kbuf, vbuf, sd, sf,
                                                     inP, inQ, inO, sumP, sumQ, sumO);
    wkv_chunk_scan<<<(BC + 255) / 256, 256, 0, stream>>>(sumP, sumQ, sumO,
                                                         inP, inQ, inO, sd, 1);
    // ---- pass-2 replay, emits a2 = bf16(y * sr) into xs buffer
    wkv_replay1<<<nwkv / 256, 256, 0, stream>>>(kbuf, vbuf, srb, xs,
                                                sd, sf, inP, inQ, inO);

    gemm_bt<1, 6><<<(MROWS / 128) * (CDIM / 128), 256, 0, stream>>>(
        xs, wo, nullptr, nullptr, nullptr, out);
}

// Round 5
// 571.117 us; speedup vs baseline: 1.2792x; 1.0486x over previous
//
#include <hip/hip_runtime.h>
#include <hip/hip_bf16.h>
#include <hip/hip_fp16.h>

#define T_SEQ 4096
#define CDIM  768
#define BDIM  8
#define MROWS (BDIM * T_SEQ)   // 32768
#define NKVR  (3 * CDIM)       // 2304
#define CHL   32               // chunk length (half a raster row)
#define NCH   (T_SEQ / CHL)    // 128 chunks
#define BC    (BDIM * CDIM)    // 6144 independent recurrences

typedef __attribute__((ext_vector_type(8))) short   short8;
typedef __attribute__((ext_vector_type(4))) float   floatx4;
typedef unsigned short ushort_t;
typedef unsigned int   uint_t;
struct ushort4_t { ushort_t x, y, z, w; };

__device__ __forceinline__ ushort_t f2b(float f) {
    __hip_bfloat16 h = __float2bfloat16(f);
    return *(ushort_t*)&h;
}
__device__ __forceinline__ float b2f(ushort_t s) {
    __hip_bfloat16 h;
    *(ushort_t*)&h = s;
    return __bfloat162float(h);
}
__device__ __forceinline__ ushort_t f2h(float f) {
    __half h = __float2half(f);
    return *(ushort_t*)&h;
}
__device__ __forceinline__ float h2f(ushort_t s) {
    __half h;
    *(ushort_t*)&h = s;
    return __half2float(h);
}

__device__ __forceinline__ void gload_lds16(const void* g, void* l) {
    __builtin_amdgcn_global_load_lds(
        (const __attribute__((address_space(1))) void*)g,
        (__attribute__((address_space(3))) void*)l, 16, 0, 0);
}

// SHIFTS table: channel group i = c/32 gets shift (dy, dx); out[y][x] = in[y-dy][x-dx]
__constant__ int c_dy[24] = {0,0,1,-1,1,-1,1,-1,0,0,2,-2,2,-2,2,-2,2,1,2,1,-2,-1,-2,-1};
__constant__ int c_dx[24] = {1,-1,0,0,1,-1,-1,1,2,-2,0,0,2,-2,-2,2,1,2,-1,-2,1,2,-1,-2};

// ---------------------------------------------------------------- weights -> bf16
__global__ void cvt_weights(const float* __restrict__ kw, const float* __restrict__ vw,
                            const float* __restrict__ rw, const float* __restrict__ ow,
                            ushort_t* __restrict__ wkvr, ushort_t* __restrict__ wo) {
    int i = blockIdx.x * 256 + threadIdx.x;
    if (i < CDIM * CDIM) {
        wkvr[i]                   = f2b(kw[i]);
        wkvr[i + CDIM * CDIM]     = f2b(vw[i]);
        wkvr[i + 2 * CDIM * CDIM] = f2b(rw[i]);
        wo[i]                     = f2b(ow[i]);
    }
}

// ------------------------------------------------- shift + zigzag reorder + bf16
__global__ void shift_zigzag(const float* __restrict__ x, ushort_t* __restrict__ xs) {
    size_t i = (size_t)blockIdx.x * 256 + threadIdx.x;   // over MROWS*CDIM/4
    if (i >= (size_t)MROWS * (CDIM / 4)) return;
    int c4 = (int)(i % (CDIM / 4)) * 4;
    size_t bt = i / (CDIM / 4);
    int tz = (int)(bt % T_SEQ);
    int b  = (int)(bt / T_SEQ);
    int r = tz >> 6, pos = tz & 63;
    int xcol = (r & 1) ? (63 - pos) : pos;
    int g = c4 >> 5;
    int ys = r - c_dy[g];
    int xsrc = xcol - c_dx[g];
    float4 val = {0.f, 0.f, 0.f, 0.f};
    if ((unsigned)ys < 64u && (unsigned)xsrc < 64u)
        val = *(const float4*)(x + ((size_t)b * T_SEQ + (size_t)(ys * 64 + xsrc)) * CDIM + c4);
    ushort4_t o;
    o.x = f2b(val.x); o.y = f2b(val.y); o.z = f2b(val.z); o.w = f2b(val.w);
    *(ushort4_t*)(xs + bt * CDIM + c4) = o;
}

// ---------------------------------------------------------------- bf16 MFMA GEMM
// C[m,n] = sum_k A[m,k] * W[n,k]; 128x128 tile, BK=64 (12 barriers), 256 thr.
// XCD swizzle: all NB n-blocks of an m-strip share one XCD (L2-hot A + W).
// Staging: thread t loads global chunk gc = (t&7)^(row&7) into LDS slot t&7
// (global_load_lds requires lane-contiguous LDS dest); reads un-swizzle ->
// 2-way bank aliasing (free).
// MODE 0 (NB=18): nb/6==0 -> k (fp16, low half of kv pair), ==1 -> v (high
// half), ==2 -> sigmoid(r) bf16. MODE 1 (NB=6): fp32 out.
template <int MODE, int NB>
__global__ __launch_bounds__(256, 3) void gemm_bt(
    const ushort_t* __restrict__ A, const ushort_t* __restrict__ Bw,
    ushort_t* __restrict__ kvb, ushort_t* __restrict__ out_sr,
    float* __restrict__ out_f) {
    __shared__ ushort_t As[128 * 64];
    __shared__ ushort_t Bs[128 * 64];
    const int p    = blockIdx.x;
    const int xcd  = p & 7;
    const int s    = p >> 3;
    const int mb   = xcd + 8 * (s / NB);
    const int nb   = s % NB;
    const int m0   = mb * 128;
    const int n0   = nb * 128;
    const int t    = threadIdx.x;
    const int lane = t & 63;
    const int wv   = t >> 6;
    const int wm   = (wv & 1) * 64;
    const int wn   = (wv >> 1) * 64;
    const int srow = t >> 3;   // 0..31
    const int sch  = t & 7;    // lds slot chunk
    const int l15  = lane & 15;
    const int l4   = lane >> 4;

    floatx4 acc[4][4];
#pragma unroll
    for (int i = 0; i < 4; i++)
#pragma unroll
        for (int j = 0; j < 4; j++) acc[i][j] = (floatx4){0.f, 0.f, 0.f, 0.f};

    for (int kk = 0; kk < CDIM; kk += 64) {
        __syncthreads();
#pragma unroll
        for (int j = 0; j < 4; j++) {
            const int rowA = 32 * j + srow;
            const int gc   = sch ^ (rowA & 7);
            gload_lds16(A  + (size_t)(m0 + rowA) * CDIM + kk + gc * 8,
                        (void*)(As + j * 2048 + t * 8));
            gload_lds16(Bw + (size_t)(n0 + rowA) * CDIM + kk + gc * 8,
                        (void*)(Bs + j * 2048 + t * 8));
        }
        __syncthreads();
#pragma unroll
        for (int k2 = 0; k2 < 2; k2++) {
            short8 af[4], bfv[4];
#pragma unroll
            for (int mi = 0; mi < 4; mi++) {
                int ra = wm + mi * 16 + l15;
                int c  = k2 * 4 + l4;
                af[mi] = *(const short8*)(As + ra * 64 + ((c ^ (ra & 7)) << 3));
            }
#pragma unroll
            for (int ni = 0; ni < 4; ni++) {
                int rb = wn + ni * 16 + l15;
                int c  = k2 * 4 + l4;
                bfv[ni] = *(const short8*)(Bs + rb * 64 + ((c ^ (rb & 7)) << 3));
            }
#pragma unroll
            for (int mi = 0; mi < 4; mi++)
#pragma unroll
                for (int ni = 0; ni < 4; ni++)
                    acc[mi][ni] = __builtin_amdgcn_mfma_f32_16x16x32_bf16(
                        af[mi], bfv[ni], acc[mi][ni], 0, 0, 0);
        }
    }

    const int region = (MODE == 0) ? (nb / 6) : 0;
    const int ncb = n0 - region * CDIM;
#pragma unroll
    for (int mi = 0; mi < 4; mi++) {
#pragma unroll
        for (int ni = 0; ni < 4; ni++) {
            int nc = ncb + wn + ni * 16 + l15;
#pragma unroll
            for (int r = 0; r < 4; r++) {
                int mg = m0 + wm + mi * 16 + l4 * 4 + r;
                float val = acc[mi][ni][r];
                if (MODE == 0) {
                    if (region == 0)
                        kvb[((size_t)mg * CDIM + nc) * 2] = f2h(val);
                    else if (region == 1)
                        kvb[((size_t)mg * CDIM + nc) * 2 + 1] = f2h(val);
                    else
                        out_sr[(size_t)mg * CDIM + nc] =
                            f2b(1.0f / (1.0f + __expf(-val)));
                } else {
                    out_f[(size_t)mg * CDIM + (n0 + wn + ni * 16 + l15)] = val;
                }
            }
        }
    }
}

// ------------------------------------------------------------- WKV chunked scan
// Recurrence: P' = e^w P + e^k v ; state max-normalized as (p,q,o).
// kvbuf: packed uint per (row, c): low half = k (fp16), high half = v/y (fp16).
// PASS 0 sequence = zigzag row order (buffer row order).
// PASS 1 sequence = raster order; CHL=32 chunk remap (verified):
//   pass-1 chunk ch's rows form pass-2 chunk idx2 = (ch&2) ? ch^1 : ch,
//   traversed in reverse iff (ch>>1)&1.

// Phase A (pass 0): per-chunk local summary from empty state.
__global__ __launch_bounds__(256) void wkv_chunk_sum0(
    const uint_t* __restrict__ kvbuf, const float* __restrict__ sd,
    float* __restrict__ sumP, float* __restrict__ sumQ, float* __restrict__ sumO) {
    int gid = blockIdx.x * 256 + threadIdx.x;
    int bc = gid % BC;
    int ch = gid / BC;
    int b = bc / CDIM, c = bc % CDIM;
    const float w = sd[c] * (1.0f / (float)T_SEQ);
    const uint_t* kv = kvbuf + ((size_t)b * T_SEQ + ch * CHL) * CDIM + c;
    float p = 0.f, q = 0.f, o = -1e38f;
#pragma unroll 8
    for (int i = 0; i < CHL; i++) {
        uint_t u = kv[(size_t)i * CDIM];
        float kt = h2f((ushort_t)(u & 0xffff)), vt = h2f((ushort_t)(u >> 16));
        float wo_ = w + o;
        float no2 = fmaxf(wo_, kt);
        float A2 = __expf(wo_ - no2), B2 = __expf(kt - no2);
        p = A2 * p + B2 * vt;
        q = A2 * q + B2;
        o = no2;
    }
    size_t idx = (size_t)ch * BC + bc;
    sumP[idx] = p; sumQ[idx] = q; sumO[idx] = o;
}

// Phase B: sequential combine of chunk summaries; writes incoming state per chunk.
__global__ __launch_bounds__(256) void wkv_chunk_scan(
    const float* __restrict__ sumP, const float* __restrict__ sumQ,
    const float* __restrict__ sumO,
    float* __restrict__ inP, float* __restrict__ inQ, float* __restrict__ inO,
    const float* __restrict__ sd, int pass) {
    int bc = blockIdx.x * 256 + threadIdx.x;
    if (bc >= BC) return;
    int c = bc % CDIM;
    const float w = sd[pass * CDIM + c] * (1.0f / (float)T_SEQ);
    const float Lw = w * (float)CHL;
    float p = 0.f, q = 0.f, o = -1e38f;
    for (int ch = 0; ch < NCH; ch++) {
        size_t idx = (size_t)ch * BC + bc;
        inP[idx] = p; inQ[idx] = q; inO[idx] = o;
        float Pc = sumP[idx], Qc = sumQ[idx], Oc = sumO[idx];
        float ow_ = o + Lw;
        float no = fmaxf(ow_, Oc);
        float e1 = __expf(ow_ - no), e2 = __expf(Oc - no);
        p = e1 * p + e2 * Pc;
        q = e1 * q + e2 * Qc;
        o = no;
    }
}

// Phase C fused: replay pass-1 chunk (y -> v-half of kvbuf, y kept in regs,
// FULLY unrolled so kv/yv stay in registers), then pass-2 chunk summary over
// the same rows in raster traversal.
__global__ __launch_bounds__(256) void wkv_replay0_sum1(
    uint_t* __restrict__ kvbuf,
    const float* __restrict__ sd, const float* __restrict__ sf,
    const float* __restrict__ inP, const float* __restrict__ inQ,
    const float* __restrict__ inO,
    float* __restrict__ sumP, float* __restrict__ sumQ, float* __restrict__ sumO) {
    int gid = blockIdx.x * 256 + threadIdx.x;
    int bc = gid % BC;
    int ch = gid / BC;
    int b = bc / CDIM, c = bc % CDIM;
    const float w1 = sd[c] * (1.0f / (float)T_SEQ);
    const float u1 = sf[c] * (1.0f / (float)T_SEQ);
    uint_t* kv = kvbuf + ((size_t)b * T_SEQ + ch * CHL) * CDIM + c;
    size_t idx = (size_t)ch * BC + bc;
    float p = inP[idx], q = inQ[idx], o = inO[idx];
    float yv[CHL];
    float kvk[CHL];
#pragma unroll
    for (int i = 0; i < CHL; i++) {
        uint_t u = kv[(size_t)i * CDIM];
        float kt = h2f((ushort_t)(u & 0xffff)), vt = h2f((ushort_t)(u >> 16));
        kvk[i] = kt;
        float uk = u1 + kt;
        float no = fmaxf(o, uk);
        float Ae = __expf(o - no), Be = __expf(uk - no);
        float y = (Ae * p + Be * vt) / (Ae * q + Be);
        float wo_ = w1 + o;
        float no2 = fmaxf(wo_, kt);
        float A2 = __expf(wo_ - no2), B2 = __expf(kt - no2);
        p = A2 * p + B2 * vt;
        q = A2 * q + B2;
        o = no2;
        yv[i] = y;
        ((ushort_t*)&kv[(size_t)i * CDIM])[1] = f2h(y);   // overwrite v-half
    }
    // pass-2 summary over same rows; raster traversal
    const float w2 = sd[CDIM + c] * (1.0f / (float)T_SEQ);
    float p2 = 0.f, q2 = 0.f, o2 = -1e38f;
    const bool rev = (ch >> 1) & 1;
#pragma unroll
    for (int j = 0; j < CHL; j++) {
        int i = rev ? (CHL - 1 - j) : j;
        float kt = kvk[i], vt = yv[i];
        float wo_ = w2 + o2;
        float no2 = fmaxf(wo_, kt);
        float A2 = __expf(wo_ - no2), B2 = __expf(kt - no2);
        p2 = A2 * p2 + B2 * vt;
        q2 = A2 * q2 + B2;
        o2 = no2;
    }
    size_t idx2 = (size_t)((ch & 2) ? (ch ^ 1) : ch) * BC + bc;
    sumP[idx2] = p2; sumQ[idx2] = q2; sumO[idx2] = o2;
}

// Phase C (pass 1): replay raster-order chunk ch, emit a2 = bf16(y * sr).
__global__ __launch_bounds__(256) void wkv_replay1(
    const uint_t* __restrict__ kvbuf,
    const ushort_t* __restrict__ srb, ushort_t* __restrict__ a2,
    const float* __restrict__ sd, const float* __restrict__ sf,
    const float* __restrict__ inP, const float* __restrict__ inQ,
    const float* __restrict__ inO) {
    int gid = blockIdx.x * 256 + threadIdx.x;
    int bc = gid % BC;
    int ch = gid / BC;
    int b = bc / CDIM, c = bc % CDIM;
    const float w = sd[CDIM + c] * (1.0f / (float)T_SEQ);
    const float u = sf[CDIM + c] * (1.0f / (float)T_SEQ);
    size_t base = (size_t)b * T_SEQ * CDIM + c;
    size_t idx = (size_t)ch * BC + bc;
    float p = inP[idx], q = inQ[idx], o = inO[idx];
    const int r = ch >> 1;
    const int pos0 = (ch & 1) * CHL;
#pragma unroll 8
    for (int i = 0; i < CHL; i++) {
        int pos = pos0 + i;
        int col = (r & 1) ? (63 - pos) : pos;
        size_t off = base + (size_t)(r * 64 + col) * CDIM;
        uint_t uu = kvbuf[off];
        float kt = h2f((ushort_t)(uu & 0xffff)), vt = h2f((ushort_t)(uu >> 16));
        float uk = u + kt;
        float no = fmaxf(o, uk);
        float Ae = __expf(o - no), Be = __expf(uk - no);
        float y = (Ae * p + Be * vt) / (Ae * q + Be);
        float wo_ = w + o;
        float no2 = fmaxf(wo_, kt);
        float A2 = __expf(wo_ - no2), B2 = __expf(kt - no2);
        p = A2 * p + B2 * vt;
        q = A2 * q + B2;
        o = no2;
        a2[off] = f2b(y * b2f(srb[off]));
    }
}

// ----------------------------------------------------------------------- launch
extern "C" void kernel_launch(void* const* d_in, const int* in_sizes, int n_in,
                              void* d_out, int out_size, void* d_ws, size_t ws_size,
                              hipStream_t stream) {
    (void)in_sizes; (void)n_in; (void)out_size; (void)ws_size;
    const float* x  = (const float*)d_in[0];
    const float* kw = (const float*)d_in[1];
    const float* vw = (const float*)d_in[2];
    const float* rw = (const float*)d_in[3];
    const float* ow = (const float*)d_in[4];
    const float* sd = (const float*)d_in[5];
    const float* sf = (const float*)d_in[6];
    float* out = (float*)d_out;

    char* ws = (char*)d_ws;
    size_t off = 0;
    auto alloc = [&](size_t bytes) -> void* {
        void* p = ws + off;
        off += (bytes + 255) & ~(size_t)255;
        return p;
    };
    ushort_t* xs   = (ushort_t*)alloc((size_t)MROWS * CDIM * 2);  // reused as a2
    ushort_t* kvb  = (ushort_t*)alloc((size_t)MROWS * CDIM * 4);  // packed (k,v) fp16
    ushort_t* srb  = (ushort_t*)alloc((size_t)MROWS * CDIM * 2);  // bf16
    ushort_t* wkvr = (ushort_t*)alloc((size_t)NKVR * CDIM * 2);
    ushort_t* wo   = (ushort_t*)alloc((size_t)CDIM * CDIM * 2);
    float*    sumP = (float*)   alloc((size_t)NCH * BC * 4);
    float*    sumQ = (float*)   alloc((size_t)NCH * BC * 4);
    float*    sumO = (float*)   alloc((size_t)NCH * BC * 4);
    float*    inP  = (float*)   alloc((size_t)NCH * BC * 4);
    float*    inQ  = (float*)   alloc((size_t)NCH * BC * 4);
    float*    inO  = (float*)   alloc((size_t)NCH * BC * 4);

    cvt_weights<<<(CDIM * CDIM + 255) / 256, 256, 0, stream>>>(kw, vw, rw, ow, wkvr, wo);
    shift_zigzag<<<(int)(((size_t)MROWS * (CDIM / 4) + 255) / 256), 256, 0, stream>>>(x, xs);
    gemm_bt<0, 18><<<(MROWS / 128) * (NKVR / 128), 256, 0, stream>>>(
        xs, wkvr, kvb, srb, nullptr);

    const int nwkv = NCH * BC;  // 786432 threads
    wkv_chunk_sum0<<<nwkv / 256, 256, 0, stream>>>((uint_t*)kvb, sd, sumP, sumQ, sumO);
    wkv_chunk_scan<<<(BC + 255) / 256, 256, 0, stream>>>(sumP, sumQ, sumO,
                                                         inP, inQ, inO, sd, 0);
    wkv_replay0_sum1<<<nwkv / 256, 256, 0, stream>>>((uint_t*)kvb, sd, sf,
                                                     inP, inQ, inO, sumP, sumQ, sumO);
    wkv_chunk_scan<<<(BC + 255) / 256, 256, 0, stream>>>(sumP, sumQ, sumO,
                                                         inP, inQ, inO, sd, 1);
    wkv_replay1<<<nwkv / 256, 256, 0, stream>>>((uint_t*)kvb, srb, xs,
                                                sd, sf, inP, inQ, inO);

    gemm_bt<1, 6><<<(MROWS / 128) * (CDIM / 128), 256, 0, stream>>>(
        xs, wo, nullptr, nullptr, out);
}